// Round 2
// baseline (947.224 us; speedup 1.0000x reference)
//
#include <hip/hip_runtime.h>
#include <hip/hip_bf16.h>

// GhostLinear: out[m,n] = sum_k x[m,k] * (lut[idx[n,k]] * scale[n])
// M=16384, N=4096, K=4096. fp32 in/out, bf16 MFMA compute.
// Pipeline: cvt_x (fp32->bf16), dequant_w (gather+scale->bf16), 256^2 8-phase GEMM.

typedef __attribute__((ext_vector_type(8))) short bf16x8;
typedef __attribute__((ext_vector_type(4))) float f32x4;

static constexpr long M_ = 16384;
static constexpr int  N_ = 4096;
static constexpr int  K_ = 4096;

#define DEVI __device__ __forceinline__
typedef __attribute__((address_space(1))) const void* as1_cvp;
typedef __attribute__((address_space(3))) void*       as3_vp;

DEVI void gload_lds16(const void* g, void* l) {
    __builtin_amdgcn_global_load_lds((as1_cvp)g, (as3_vp)l, 16, 0, 0);
}

// ---------------- prep kernels ----------------

__global__ __launch_bounds__(256) void cvt_x_kernel(
    const float* __restrict__ x, __hip_bfloat16* __restrict__ xb, long total) {
    long t = (long)blockIdx.x * blockDim.x + threadIdx.x;
    long stride = (long)gridDim.x * blockDim.x;
    for (long e = t * 8; e < total; e += stride * 8) {
        float4 f0 = *(const float4*)(x + e);
        float4 f1 = *(const float4*)(x + e + 4);
        union { __hip_bfloat16 h[8]; int4 v4; } u;
        u.h[0] = __float2bfloat16(f0.x); u.h[1] = __float2bfloat16(f0.y);
        u.h[2] = __float2bfloat16(f0.z); u.h[3] = __float2bfloat16(f0.w);
        u.h[4] = __float2bfloat16(f1.x); u.h[5] = __float2bfloat16(f1.y);
        u.h[6] = __float2bfloat16(f1.z); u.h[7] = __float2bfloat16(f1.w);
        *(int4*)(xb + e) = u.v4;
    }
}

__global__ __launch_bounds__(256) void dequant_w_kernel(
    const int* __restrict__ idx, const float* __restrict__ lut,
    const float* __restrict__ scale, __hip_bfloat16* __restrict__ wb) {
    const long total = (long)N_ * K_;
    long t = (long)blockIdx.x * blockDim.x + threadIdx.x;
    long stride = (long)gridDim.x * blockDim.x;
    for (long e = t * 8; e < total; e += stride * 8) {
        int4 i0 = *(const int4*)(idx + e);
        int4 i1 = *(const int4*)(idx + e + 4);
        float s = scale[e >> 12];   // row = e / 4096; 8-elem chunk never crosses rows
        union { __hip_bfloat16 h[8]; int4 v4; } u;
        u.h[0] = __float2bfloat16(lut[i0.x] * s);
        u.h[1] = __float2bfloat16(lut[i0.y] * s);
        u.h[2] = __float2bfloat16(lut[i0.z] * s);
        u.h[3] = __float2bfloat16(lut[i0.w] * s);
        u.h[4] = __float2bfloat16(lut[i1.x] * s);
        u.h[5] = __float2bfloat16(lut[i1.y] * s);
        u.h[6] = __float2bfloat16(lut[i1.z] * s);
        u.h[7] = __float2bfloat16(lut[i1.w] * s);
        *(int4*)(wb + e) = u.v4;
    }
}

// ---------------- 256^2 8-phase GEMM (T2+T3+T4+T5) ----------------
// LDS layout (bf16 elems): A: [buf][ks][row 0..255][32 cols], chunk-swizzled; B at +32768.
// Swizzle: 16B chunk index c' = c ^ ((row>>1)&3). Staging keeps LDS linear and
// pre-swizzles the GLOBAL source (same involution on read side).

__global__ __launch_bounds__(512, 2)
void gemm8_kernel(const __hip_bfloat16* __restrict__ Ab,
                  const __hip_bfloat16* __restrict__ Wb,
                  float* __restrict__ out) {
    __shared__ short lds[65536];   // 128 KiB

    static constexpr int NKT = K_ / 64;      // 64 K-tiles
    const int NWG = (int)(M_ / 256) * (N_ / 256);   // 1024, %8==0 -> bijective swizzle
    int bid = blockIdx.x;
    int swz = (bid & 7) * (NWG >> 3) + (bid >> 3);
    const long m0 = (long)(swz >> 4) * 256;  // 16 N-tiles per M-row
    const int  n0 = (swz & 15) * 256;

    const int t    = threadIdx.x;
    const int lane = t & 63;
    const int w    = t >> 6;
    const int wm   = w >> 2;     // 0..1  -> A rows [wm*128, wm*128+128)
    const int wn   = w & 3;      // 0..3  -> B rows [wn*64, wn*64+64)
    const int fr   = lane & 15;
    const int fq   = lane >> 4;

    // staging: round rd covers rows rd*128 + (t>>2); 4 threads x 16B per 64B row
    const int srow0 = t >> 2;
    const int spc   = t & 3;                       // phys 16B chunk
    // read-side swizzled chunk (shorts): (row>>1)&3 == (fr>>1)&3 since frag rows step by 16
    const int rchunk = (fq ^ ((fr >> 1) & 3)) * 8;

    auto stageA = [&](int kt2, int ks, int d) {
#pragma unroll
        for (int rd = 0; rd < 2; ++rd) {
            const int row = rd * 128 + srow0;
            const int lc  = spc ^ ((row >> 1) & 3);           // logical chunk for this phys slot
            const __hip_bfloat16* g = Ab + (m0 + row) * (long)K_ + kt2 * 64 + ks * 32 + lc * 8;
            gload_lds16(g, &lds[d * 16384 + ks * 8192 + row * 32 + spc * 8]);
        }
    };
    auto stageB = [&](int kt2, int ks, int d) {
#pragma unroll
        for (int rd = 0; rd < 2; ++rd) {
            const int row = rd * 128 + srow0;
            const int lc  = spc ^ ((row >> 1) & 3);
            const __hip_bfloat16* g = Wb + (long)(n0 + row) * K_ + kt2 * 64 + ks * 32 + lc * 8;
            gload_lds16(g, &lds[32768 + d * 16384 + ks * 8192 + row * 32 + spc * 8]);
        }
    };

    f32x4 acc[8][4] = {};
    bf16x8 aF[4], bF[4];

#define PHASE(KS, MH, STAGE_STMT, VMCNT_STMT) do {                                        \
    if ((MH) == 0) {                                                                      \
        _Pragma("unroll")                                                                 \
        for (int j = 0; j < 4; ++j)                                                       \
            bF[j] = *(const bf16x8*)&lds[32768 + d * 16384 + (KS) * 8192 +                \
                                         (wn * 64 + j * 16 + fr) * 32 + rchunk];          \
    }                                                                                     \
    _Pragma("unroll")                                                                     \
    for (int ii = 0; ii < 4; ++ii)                                                        \
        aF[ii] = *(const bf16x8*)&lds[d * 16384 + (KS) * 8192 +                           \
                                      (wm * 128 + ((MH) * 4 + ii) * 16 + fr) * 32 + rchunk]; \
    STAGE_STMT;                                                                           \
    __builtin_amdgcn_s_barrier();                                                         \
    asm volatile("s_waitcnt lgkmcnt(0)" ::: "memory");                                    \
    __builtin_amdgcn_sched_barrier(0);                                                    \
    __builtin_amdgcn_s_setprio(1);                                                        \
    _Pragma("unroll")                                                                     \
    for (int ii = 0; ii < 4; ++ii)                                                        \
        _Pragma("unroll")                                                                 \
        for (int j = 0; j < 4; ++j)                                                       \
            acc[(MH) * 4 + ii][j] = __builtin_amdgcn_mfma_f32_16x16x32_bf16(              \
                aF[ii], bF[j], acc[(MH) * 4 + ii][j], 0, 0, 0);                           \
    __builtin_amdgcn_s_setprio(0);                                                        \
    VMCNT_STMT;                                                                           \
    __builtin_amdgcn_s_barrier();                                                         \
} while (0)

    // prologue: fully stage tile 0 into buf 0 (8 loads/thread), wait for ks0 half
    stageA(0, 0, 0); stageB(0, 0, 0); stageA(0, 1, 0); stageB(0, 1, 0);
    asm volatile("s_waitcnt vmcnt(4)" ::: "memory");
    __builtin_amdgcn_s_barrier();

    for (int kt = 0; kt < NKT; ++kt) {
        const int d  = kt & 1;
        const int nd = d ^ 1;
        const int nk = (kt + 1 < NKT) ? kt + 1 : 0;   // last tile: harmless re-stage of tile 0
        // steady state: exactly 8 loads/thread outstanding at each vmcnt(4)
        PHASE(0, 0, stageA(nk, 0, nd), );
        PHASE(0, 1, stageB(nk, 0, nd), asm volatile("s_waitcnt vmcnt(4)" ::: "memory"));
        PHASE(1, 0, stageA(nk, 1, nd), );
        PHASE(1, 1, stageB(nk, 1, nd), asm volatile("s_waitcnt vmcnt(4)" ::: "memory"));
    }
#undef PHASE

    // epilogue: C/D layout col = lane&15 (N dim), row = fq*4 + v (M dim)  [m89/m91]
#pragma unroll
    for (int i = 0; i < 8; ++i) {
        const long mrow = m0 + wm * 128 + i * 16 + fq * 4;
#pragma unroll
        for (int j = 0; j < 4; ++j) {
            const int ncol = n0 + wn * 64 + j * 16 + fr;
#pragma unroll
            for (int v = 0; v < 4; ++v)
                out[(mrow + v) * N_ + ncol] = acc[i][j][v];
        }
    }
}

// ---------------- fallback fused GEMM (only if ws too small) ----------------

__global__ __launch_bounds__(256)
void gemm_fused_kernel(const float* __restrict__ Af, const int* __restrict__ idx,
                       const float* __restrict__ lut, const float* __restrict__ scale,
                       float* __restrict__ out) {
    constexpr int BM = 128, BN = 128, BK = 32;
    __shared__ __hip_bfloat16 As[BM * BK];
    __shared__ __hip_bfloat16 Bs[BN * BK];

    const int NT  = N_ / BN;
    const int NWG = (int)(M_ / BM) * NT;
    int bid = blockIdx.x;
    int swz = (bid & 7) * (NWG >> 3) + (bid >> 3);
    int mt = swz / NT, nt = swz % NT;
    const long m0 = (long)mt * BM;
    const int  n0 = nt * BN;

    const int t = threadIdx.x, lane = t & 63, wave = t >> 6;
    const int wm = wave >> 1, wn = wave & 1;
    const int sr = t >> 2, sc = (t & 3) * 8;
    const int fr = lane & 15, fq = lane >> 4;

    f32x4 acc[4][4] = {};
    for (int kt = 0; kt < K_ / BK; ++kt) {
        const int k0 = kt * BK;
#pragma unroll
        for (int it = 0; it < 2; ++it) {
            const int r = it * 64 + sr;
            const float* asrc = Af + (m0 + r) * K_ + k0 + sc;
            float4 f0 = *(const float4*)asrc;
            float4 f1 = *(const float4*)(asrc + 4);
            union { __hip_bfloat16 h[8]; int4 v4; } ua;
            ua.h[0] = __float2bfloat16(f0.x); ua.h[1] = __float2bfloat16(f0.y);
            ua.h[2] = __float2bfloat16(f0.z); ua.h[3] = __float2bfloat16(f0.w);
            ua.h[4] = __float2bfloat16(f1.x); ua.h[5] = __float2bfloat16(f1.y);
            ua.h[6] = __float2bfloat16(f1.z); ua.h[7] = __float2bfloat16(f1.w);
            *(int4*)&As[r * BK + sc] = ua.v4;

            const int* isrc = idx + (long)(n0 + r) * K_ + k0 + sc;
            int4 i0 = *(const int4*)isrc;
            int4 i1 = *(const int4*)(isrc + 4);
            float s = scale[n0 + r];
            union { __hip_bfloat16 h[8]; int4 v4; } ub;
            ub.h[0] = __float2bfloat16(lut[i0.x] * s);
            ub.h[1] = __float2bfloat16(lut[i0.y] * s);
            ub.h[2] = __float2bfloat16(lut[i0.z] * s);
            ub.h[3] = __float2bfloat16(lut[i0.w] * s);
            ub.h[4] = __float2bfloat16(lut[i1.x] * s);
            ub.h[5] = __float2bfloat16(lut[i1.y] * s);
            ub.h[6] = __float2bfloat16(lut[i1.z] * s);
            ub.h[7] = __float2bfloat16(lut[i1.w] * s);
            *(int4*)&Bs[r * BK + sc] = ub.v4;
        }
        __syncthreads();

        bf16x8 af[4], bf[4];
#pragma unroll
        for (int i = 0; i < 4; ++i)
            af[i] = *(const bf16x8*)&As[(wm * 64 + i * 16 + fr) * BK + fq * 8];
#pragma unroll
        for (int j = 0; j < 4; ++j)
            bf[j] = *(const bf16x8*)&Bs[(wn * 64 + j * 16 + fr) * BK + fq * 8];
#pragma unroll
        for (int i = 0; i < 4; ++i)
#pragma unroll
            for (int j = 0; j < 4; ++j)
                acc[i][j] = __builtin_amdgcn_mfma_f32_16x16x32_bf16(af[i], bf[j], acc[i][j], 0, 0, 0);
        __syncthreads();
    }
#pragma unroll
    for (int i = 0; i < 4; ++i) {
        const long mrow = m0 + wm * 64 + i * 16 + fq * 4;
#pragma unroll
        for (int j = 0; j < 4; ++j) {
            const int ncol = n0 + wn * 64 + j * 16 + fr;
#pragma unroll
            for (int v = 0; v < 4; ++v)
                out[(mrow + v) * N_ + ncol] = acc[i][j][v];
        }
    }
}

// ---------------- launch ----------------

extern "C" void kernel_launch(void* const* d_in, const int* in_sizes, int n_in,
                              void* d_out, int out_size, void* d_ws, size_t ws_size,
                              hipStream_t stream) {
    const float* x     = (const float*)d_in[0];
    const float* scale = (const float*)d_in[1];
    const float* lut   = (const float*)d_in[2];
    const int*   idx   = (const int*)d_in[3];
    float* out = (float*)d_out;

    const size_t xb_bytes = (size_t)M_ * K_ * sizeof(__hip_bfloat16);   // 128 MB
    const size_t wb_bytes = (size_t)N_ * K_ * sizeof(__hip_bfloat16);   //  32 MB

    if (ws_size >= xb_bytes + wb_bytes) {
        __hip_bfloat16* xb = (__hip_bfloat16*)d_ws;
        __hip_bfloat16* wb = (__hip_bfloat16*)((char*)d_ws + xb_bytes);
        cvt_x_kernel<<<4096, 256, 0, stream>>>(x, xb, M_ * (long)K_);
        dequant_w_kernel<<<2048, 256, 0, stream>>>(idx, lut, scale, wb);
        const int grid = (int)(M_ / 256) * (N_ / 256);   // 1024
        gemm8_kernel<<<grid, 512, 0, stream>>>(xb, wb, out);
    } else {
        const int grid = (int)(M_ / 128) * (N_ / 128);   // 4096
        gemm_fused_kernel<<<grid, 256, 0, stream>>>(x, idx, lut, scale, out);
    }
}